// Round 6
// baseline (476.050 us; speedup 1.0000x reference)
//
#include <hip/hip_runtime.h>
#include <hip/hip_fp16.h>

#define NN 50000
#define NE 300000
#define ETILES (NE / 16)        // 18750
#define NTILES (NN / 16)        // 3125
#define WLDS_STRIDE 136         // 128 + 8 f16 pad

typedef _Float16 f16;
typedef _Float16 f16x4 __attribute__((ext_vector_type(4)));
typedef _Float16 f16x8 __attribute__((ext_vector_type(8)));
typedef float f32x4 __attribute__((ext_vector_type(4)));

struct Idx6 { const int* p[6]; };

__device__ __forceinline__ f16x4 cvt4(float4 v) {
    f16x4 r; r.x = (f16)v.x; r.y = (f16)v.y; r.z = (f16)v.z; r.w = (f16)v.w;
    return r;
}

// ---------------- init: h/agg = 2*x (f16) AND xh = x (f16), 3 levels ----------------
__global__ void init2_kernel(const float* __restrict__ x0, const float* __restrict__ x1,
                             const float* __restrict__ x2,
                             f16* __restrict__ hbase, f16* __restrict__ xhbase) {
    const size_t i = (size_t)blockIdx.x * 256 + threadIdx.x;   // float4 idx; 9375*256 == 3*NN*16
    const int lvl = (int)(i / (NN * 16));
    const size_t li = i - (size_t)lvl * (NN * 16);
    const float* xs = (lvl == 0) ? x0 : (lvl == 1) ? x1 : x2;
    float4 v = ((const float4*)xs)[li];
    f16x4 xo, ho;
    xo.x = (f16)v.x;        xo.y = (f16)v.y;        xo.z = (f16)v.z;        xo.w = (f16)v.w;
    ho.x = (f16)(2.f*v.x);  ho.y = (f16)(2.f*v.y);  ho.z = (f16)(2.f*v.z);  ho.w = (f16)(2.f*v.w);
    ((f16x4*)(xhbase + (size_t)lvl * NN * 64))[li] = xo;
    ((f16x4*)(hbase  + (size_t)lvl * NN * 64))[li] = ho;
}

// ---------------- W transpose: Wt[c][k] = (f16)W[k][c], W is [128][64] ----------------
__global__ void wtrans_kernel(const float* __restrict__ WU, const float* __restrict__ WD,
                              f16* __restrict__ WtU, f16* __restrict__ WtD) {
    const int i = blockIdx.x * 256 + threadIdx.x;   // 32 blocks * 256 = 8192
    const int k = i >> 6, c = i & 63;
    WtU[c * 128 + k] = (f16)WU[i];
    WtD[c * 128 + k] = (f16)WD[i];
}

// ================= CSR build (counting sort by target) =================
__global__ void zero_cnt_kernel(int* __restrict__ cnt) {
    const int i = blockIdx.x * 256 + threadIdx.x;
    if (i < 6 * NN) cnt[i] = 0;
}

__global__ void hist_kernel(Idx6 idx, int* __restrict__ cnt) {
    const int e = blockIdx.x * 256 + threadIdx.x;
    const int d = blockIdx.y;
    if (e < NE) atomicAdd(&cnt[d * NN + idx.p[d][e]], 1);
}

__device__ __forceinline__ int block_incl_scan(int v, int tid, int* sb) {
    sb[tid] = v; __syncthreads();
#pragma unroll
    for (int off = 1; off < 256; off <<= 1) {
        int t = (tid >= off) ? sb[tid - off] : 0;
        __syncthreads();
        sb[tid] += t;
        __syncthreads();
    }
    return sb[tid];
}

__global__ void scan1_kernel(const int* __restrict__ cnt, int* __restrict__ rptmp,
                             int* __restrict__ bsum) {
    __shared__ int sb[256];
    const int d = blockIdx.y, tid = threadIdx.x;
    const int i = blockIdx.x * 256 + tid;
    const int v = (i < NN) ? cnt[d * NN + i] : 0;
    const int incl = block_incl_scan(v, tid, sb);
    if (i < NN) rptmp[d * NN + i] = incl - v;
    if (tid == 255) bsum[d * 256 + blockIdx.x] = incl;
}

__global__ void scan2_kernel(int* __restrict__ bsum) {
    __shared__ int sb[256];
    const int d = blockIdx.x, tid = threadIdx.x;
    const int v = (tid < 196) ? bsum[d * 256 + tid] : 0;
    const int incl = block_incl_scan(v, tid, sb);
    bsum[d * 256 + tid] = incl - v;   // exclusive
}

__global__ void scan3_kernel(const int* __restrict__ cnt, const int* __restrict__ rptmp,
                             const int* __restrict__ bsum,
                             int* __restrict__ rowptr, int* __restrict__ cursor) {
    const int d = blockIdx.y;
    const int i = blockIdx.x * 256 + threadIdx.x;
    if (i < NN) {
        const int v = rptmp[d * NN + i] + bsum[d * 256 + blockIdx.x];
        rowptr[d * (NN + 1) + i] = v;
        cursor[d * NN + i] = v;
        if (i == NN - 1) rowptr[d * (NN + 1) + NN] = v + cnt[d * NN + i];
    }
}

__global__ void scatter_kernel(Idx6 idx, int* __restrict__ cursor, int* __restrict__ pos) {
    const int e = blockIdx.x * 256 + threadIdx.x;
    const int d = blockIdx.y;
    if (e < NE) pos[(size_t)d * NE + e] = atomicAdd(&cursor[d * NN + idx.p[d][e]], 1);
}

// ================= Phase 1: edge MLP -> dense sorted message rows (NO atomics) =================
__global__ __launch_bounds__(256) void edge_mlp_kernel(
    const f16* __restrict__ xh,
    const int* __restrict__ ui, const int* __restrict__ di,
    const float* __restrict__ ua, const float* __restrict__ da,
    const f16* __restrict__ WtU, const f16* __restrict__ WtD,
    const float* __restrict__ bU, const float* __restrict__ bD,
    const int* __restrict__ posU, const int* __restrict__ posD,
    __half* __restrict__ mU, __half* __restrict__ mD) {

    __shared__ __align__(16) f16 Wlds[64 * WLDS_STRIDE];

    const int dir = blockIdx.y;
    const int* __restrict__ idx    = dir ? di : ui;
    const float* __restrict__ attr = dir ? da : ua;
    const f16* __restrict__ Wt     = dir ? WtD : WtU;
    const float* __restrict__ b    = dir ? bD : bU;
    const int* __restrict__ pos    = dir ? posD : posU;
    __half* __restrict__ m         = dir ? mD : mU;

    const int tt   = threadIdx.x;
    const int lane = tt & 63;
    const int wid  = tt >> 6;
    const int lr   = lane & 15;
    const int lg   = (lane >> 4) & 3;

    // stage W into LDS
    for (int i = tt; i < 1024; i += 256) {
        const int row = i >> 4, seg = i & 15;
        *(f16x8*)&Wlds[row * WLDS_STRIDE + seg * 8] = *(const f16x8*)&Wt[row * 128 + seg * 8];
    }
    float bf[4];
#pragma unroll
    for (int n = 0; n < 4; ++n) bf[n] = b[n * 16 + lr];
    __syncthreads();

    const int tile = blockIdx.x * 4 + wid;
    if (tile >= ETILES) return;
    const int e0 = tile << 4;

    const int src = idx[NE + e0 + lr];     // source node for row lr
    const int pv  = pos[e0 + lr];          // sorted slot for row lr

    const float4* a4 = (const float4*)attr;

    // A fragments: a[k0].j = A[lr][k0*16+4*lg+j]
    f16x4 afr[8];
#pragma unroll
    for (int k0 = 0; k0 < 4; ++k0)
        afr[k0] = *(const f16x4*)&xh[(size_t)src * 64 + k0 * 16 + 4 * lg];
#pragma unroll
    for (int k0 = 0; k0 < 4; ++k0)
        afr[4 + k0] = cvt4(a4[(size_t)(e0 + lr) * 16 + 4 * k0 + lg]);

    f32x4 acc[4];
#pragma unroll
    for (int n = 0; n < 4; ++n) acc[n] = (f32x4){0.f, 0.f, 0.f, 0.f};
#pragma unroll
    for (int k0 = 0; k0 < 8; ++k0) {
#pragma unroll
        for (int n = 0; n < 4; ++n) {
            const f16x4 wf = *(const f16x4*)&Wlds[(n * 16 + lr) * WLDS_STRIDE + k0 * 16 + 4 * lg];
            acc[n] = __builtin_amdgcn_mfma_f32_16x16x16f16(afr[k0], wf, acc[n], 0, 0, 0);
        }
    }

    // bias + relu + PLAIN packed stores to sorted slot. D[row=4*lg+j][col=n*16+lr].
#pragma unroll
    for (int j = 0; j < 4; ++j) {
        float v[4], vn[4];
#pragma unroll
        for (int n = 0; n < 4; ++n) v[n] = fmaxf(acc[n][j] + bf[n], 0.f);
#pragma unroll
        for (int n = 0; n < 4; ++n) vn[n] = __shfl_xor(v[n], 1);
        const int s = __shfl(pv, 4 * lg + j);
        __half* mp = m + (size_t)s * 64;
        if ((lane & 1) == 0) {
            *(__half2*)(mp + 0 * 16 + lr) = __floats2half2_rn(v[0], vn[0]);
            *(__half2*)(mp + 1 * 16 + lr) = __floats2half2_rn(v[1], vn[1]);
        } else {
            *(__half2*)(mp + 2 * 16 + lr - 1) = __floats2half2_rn(vn[2], v[2]);
            *(__half2*)(mp + 3 * 16 + lr - 1) = __floats2half2_rn(vn[3], v[3]);
        }
    }
}

// ================= Phase 2: CSR segment-sum + 2x -> agg (f16) =================
__global__ __launch_bounds__(256) void agg_kernel(
    const float* __restrict__ x,
    const __half* __restrict__ mU, const __half* __restrict__ mD,
    const int* __restrict__ rpU, const int* __restrict__ rpD,
    f16* __restrict__ agg) {

    const int tid  = threadIdx.x;
    const int node = blockIdx.x * 16 + (tid >> 4);   // 3125*16 == NN exactly
    const int c4   = tid & 15;

    float4 xv = ((const float4*)x)[(size_t)node * 16 + c4];
    float a0 = 2.f * xv.x, a1 = 2.f * xv.y, a2 = 2.f * xv.z, a3 = 2.f * xv.w;

    {
        const int beg = rpU[node], end = rpU[node + 1];
        for (int k = beg; k < end; ++k) {
            f16x4 mv = *(const f16x4*)((const f16*)mU + (size_t)k * 64 + c4 * 4);
            a0 += (float)mv.x; a1 += (float)mv.y; a2 += (float)mv.z; a3 += (float)mv.w;
        }
    }
    {
        const int beg = rpD[node], end = rpD[node + 1];
        for (int k = beg; k < end; ++k) {
            f16x4 mv = *(const f16x4*)((const f16*)mD + (size_t)k * 64 + c4 * 4);
            a0 += (float)mv.x; a1 += (float)mv.y; a2 += (float)mv.z; a3 += (float)mv.w;
        }
    }
    f16x4 o; o.x = (f16)a0; o.y = (f16)a1; o.z = (f16)a2; o.w = (f16)a3;
    *(f16x4*)&agg[(size_t)node * 64 + c4 * 4] = o;
}

// ================= Fallback (round-5 proven): edge MLP + f16 atomic scatter =================
__device__ __forceinline__ int ld_comb(const int* __restrict__ idx, int tile, int l5) {
    const int e0 = tile << 4;
    return idx[(l5 < 16) ? (NE + e0 + l5) : (e0 + l5 - 16)];
}

__global__ __launch_bounds__(256) void edge4_kernel(
    const f16* __restrict__ xh,
    const int* __restrict__ ui, const int* __restrict__ di,
    const float* __restrict__ ua, const float* __restrict__ da,
    const f16* __restrict__ WtU, const f16* __restrict__ WtD,
    const float* __restrict__ bU, const float* __restrict__ bD,
    __half* __restrict__ h) {

    __shared__ __align__(16) f16 Wlds[64 * WLDS_STRIDE];

    const int dir = blockIdx.y;
    const int* __restrict__ idx    = dir ? di : ui;
    const float* __restrict__ attr = dir ? da : ua;
    const f16* __restrict__ Wt     = dir ? WtD : WtU;
    const float* __restrict__ b    = dir ? bD : bU;

    const int tt   = threadIdx.x;
    const int lane = tt & 63;
    const int wid  = tt >> 6;
    const int lr   = lane & 15;
    const int lg   = (lane >> 4) & 3;
    const int l5   = lane & 31;

    for (int i = tt; i < 1024; i += 256) {
        const int row = i >> 4, seg = i & 15;
        *(f16x8*)&Wlds[row * WLDS_STRIDE + seg * 8] = *(const f16x8*)&Wt[row * 128 + seg * 8];
    }
    float bf[4];
#pragma unroll
    for (int n = 0; n < 4; ++n) bf[n] = b[n * 16 + lr];
    __syncthreads();

    const float4* a4 = (const float4*)attr;
    const int S = gridDim.x * 4;
    int t = blockIdx.x * 4 + wid;
    if (t >= ETILES) return;

    for (; t < ETILES; t += S) {
        const int e0 = t << 4;
        const int cA = ld_comb(idx, t, l5);
        const int src = __shfl(cA, lr);
        int tg[4];
#pragma unroll
        for (int j = 0; j < 4; ++j) tg[j] = __shfl(cA, 16 + 4 * lg + j);

        f16x4 afr[8];
#pragma unroll
        for (int k0 = 0; k0 < 4; ++k0)
            afr[k0] = *(const f16x4*)&xh[(size_t)src * 64 + k0 * 16 + 4 * lg];
#pragma unroll
        for (int k0 = 0; k0 < 4; ++k0)
            afr[4 + k0] = cvt4(a4[(size_t)(e0 + lr) * 16 + 4 * k0 + lg]);

        f32x4 acc[4];
#pragma unroll
        for (int n = 0; n < 4; ++n) acc[n] = (f32x4){0.f, 0.f, 0.f, 0.f};
#pragma unroll
        for (int k0 = 0; k0 < 8; ++k0)
#pragma unroll
            for (int n = 0; n < 4; ++n) {
                const f16x4 wf = *(const f16x4*)&Wlds[(n * 16 + lr) * WLDS_STRIDE + k0 * 16 + 4 * lg];
                acc[n] = __builtin_amdgcn_mfma_f32_16x16x16f16(afr[k0], wf, acc[n], 0, 0, 0);
            }

#pragma unroll
        for (int j = 0; j < 4; ++j) {
            float v[4], vn[4];
#pragma unroll
            for (int n = 0; n < 4; ++n) v[n] = fmaxf(acc[n][j] + bf[n], 0.f);
#pragma unroll
            for (int n = 0; n < 4; ++n) vn[n] = __shfl_xor(v[n], 1);
            __half* hp = h + (size_t)tg[j] * 64;
            if ((lane & 1) == 0) {
                unsafeAtomicAdd((__half2*)(hp + 0 * 16 + lr), __floats2half2_rn(v[0], vn[0]));
                unsafeAtomicAdd((__half2*)(hp + 1 * 16 + lr), __floats2half2_rn(v[1], vn[1]));
            } else {
                unsafeAtomicAdd((__half2*)(hp + 2 * 16 + lr - 1), __floats2half2_rn(vn[2], v[2]));
                unsafeAtomicAdd((__half2*)(hp + 3 * 16 + lr - 1), __floats2half2_rn(vn[3], v[3]));
            }
        }
    }
}

// ---------------- node MLP: one 16-node tile per WAVE, per-wave LDS, no barriers ----------------
__global__ __launch_bounds__(256) void node_kernel(
    const f16* __restrict__ hbase, float* __restrict__ outb,
    const float* __restrict__ W1, const float* __restrict__ b1,
    const float* __restrict__ W2, const float* __restrict__ b2) {

    __shared__ f16 Y[4][16 * 72];

    const int t    = threadIdx.x;
    const int lane = t & 63;
    const int wid  = t >> 6;
    const int lr   = lane & 15;
    const int lg   = (lane >> 4) & 3;

    f16x4 w1f[4][4], w2f[4][4];
#pragma unroll
    for (int k0 = 0; k0 < 4; ++k0) {
        const int kb = k0 * 16 + 4 * lg;
#pragma unroll
        for (int n = 0; n < 4; ++n) {
            const int c = n * 16 + lr;
            f16x4 w;
            w.x = (f16)W1[(kb + 0) * 64 + c];
            w.y = (f16)W1[(kb + 1) * 64 + c];
            w.z = (f16)W1[(kb + 2) * 64 + c];
            w.w = (f16)W1[(kb + 3) * 64 + c];
            w1f[k0][n] = w;
            w.x = (f16)W2[(kb + 0) * 64 + c];
            w.y = (f16)W2[(kb + 1) * 64 + c];
            w.z = (f16)W2[(kb + 2) * 64 + c];
            w.w = (f16)W2[(kb + 3) * 64 + c];
            w2f[k0][n] = w;
        }
    }
    float b1f[4], b2f[4];
#pragma unroll
    for (int n = 0; n < 4; ++n) {
        b1f[n] = b1[n * 16 + lr];
        b2f[n] = b2[n * 16 + lr];
    }

    const int gw     = blockIdx.x * 4 + wid;
    const int stride = gridDim.x * 4;
    for (int tile = gw; tile < 3 * NTILES; tile += stride) {
        const int lvl = tile / NTILES;
        const int n0  = (tile - lvl * NTILES) << 4;
        float* out = outb + (size_t)lvl * NN * 64;
        const f16* h16 = hbase + (size_t)lvl * NN * 64;

        f16x4 a[4];
#pragma unroll
        for (int k0 = 0; k0 < 4; ++k0)
            a[k0] = *(const f16x4*)&h16[(size_t)(n0 + lr) * 64 + k0 * 16 + 4 * lg];

        f32x4 acc[4];
#pragma unroll
        for (int n = 0; n < 4; ++n) acc[n] = (f32x4){0.f, 0.f, 0.f, 0.f};
#pragma unroll
        for (int k0 = 0; k0 < 4; ++k0)
#pragma unroll
            for (int n = 0; n < 4; ++n)
                acc[n] = __builtin_amdgcn_mfma_f32_16x16x16f16(a[k0], w1f[k0][n], acc[n], 0, 0, 0);

#pragma unroll
        for (int n = 0; n < 4; ++n)
#pragma unroll
            for (int j = 0; j < 4; ++j) {
                float v = acc[n][j] + b1f[n];
                v = v > 0.f ? v : 0.f;
                Y[wid][(4 * lg + j) * 72 + n * 16 + lr] = (f16)v;
            }

        f16x4 a2[4];
#pragma unroll
        for (int k0 = 0; k0 < 4; ++k0)
            a2[k0] = *(const f16x4*)&Y[wid][lr * 72 + k0 * 16 + 4 * lg];

        f32x4 acc2[4];
#pragma unroll
        for (int n = 0; n < 4; ++n) acc2[n] = (f32x4){0.f, 0.f, 0.f, 0.f};
#pragma unroll
        for (int k0 = 0; k0 < 4; ++k0)
#pragma unroll
            for (int n = 0; n < 4; ++n)
                acc2[n] = __builtin_amdgcn_mfma_f32_16x16x16f16(a2[k0], w2f[k0][n], acc2[n], 0, 0, 0);

#pragma unroll
        for (int n = 0; n < 4; ++n)
#pragma unroll
            for (int j = 0; j < 4; ++j) {
                float v = acc2[n][j] + b2f[n];
                v = v > 0.f ? v : 0.f;
                out[(size_t)(n0 + 4 * lg + j) * 64 + n * 16 + lr] = v;
            }
    }
}

extern "C" void kernel_launch(void* const* d_in, const int* in_sizes, int n_in,
                              void* d_out, int out_size, void* d_ws, size_t ws_size,
                              hipStream_t stream) {
    (void)in_sizes; (void)n_in; (void)out_size;

    const float* W_up   = (const float*)d_in[15];
    const float* b_up   = (const float*)d_in[16];
    const float* W_down = (const float*)d_in[17];
    const float* b_down = (const float*)d_in[18];
    const float* W1     = (const float*)d_in[19];
    const float* b1     = (const float*)d_in[20];
    const float* W2     = (const float*)d_in[21];
    const float* b2     = (const float*)d_in[22];

    const float* x0 = (const float*)d_in[0];
    const float* x1 = (const float*)d_in[5];
    const float* x2 = (const float*)d_in[10];

    // workspace layout
    size_t off = 0;
    auto alloc = [&](size_t bytes) { size_t o = off; off = (off + bytes + 255) & ~(size_t)255; return o; };
    const size_t o_xh   = alloc((size_t)3 * NN * 64 * 2);      // f16 x copies
    const size_t o_agg  = alloc((size_t)3 * NN * 64 * 2);      // f16 h/agg
    const size_t o_wt   = alloc((size_t)2 * 128 * 64 * 2);     // Wt f16
    const size_t fallback_need = off;
    const size_t o_m    = alloc((size_t)2 * NE * 64 * 2);      // message rows (2 dirs, per level reuse)
    const size_t o_pos  = alloc((size_t)6 * NE * 4);
    const size_t o_rp   = alloc((size_t)6 * (NN + 1) * 4);
    const size_t o_cur  = alloc((size_t)6 * NN * 4);
    const size_t o_rpt  = alloc((size_t)6 * NN * 4);
    const size_t o_bsum = alloc((size_t)6 * 256 * 4);
    const size_t o_cnt  = alloc((size_t)6 * NN * 4);
    const size_t full_need = off;

    char* ws = (char*)d_ws;
    f16*  xh   = (f16*)(ws + o_xh);
    f16*  agg  = (f16*)(ws + o_agg);
    f16*  WtU  = (f16*)(ws + o_wt);
    f16*  WtD  = WtU + 128 * 64;

    if (ws_size >= full_need) {
        __half* mU  = (__half*)(ws + o_m);
        __half* mD  = mU + (size_t)NE * 64;
        int* pos    = (int*)(ws + o_pos);
        int* rowptr = (int*)(ws + o_rp);
        int* cursor = (int*)(ws + o_cur);
        int* rptmp  = (int*)(ws + o_rpt);
        int* bsum   = (int*)(ws + o_bsum);
        int* cnt    = (int*)(ws + o_cnt);

        Idx6 idx;
        for (int d = 0; d < 3; ++d) {
            idx.p[2 * d + 0] = (const int*)d_in[5 * d + 1];
            idx.p[2 * d + 1] = (const int*)d_in[5 * d + 2];
        }

        // CSR build for all 6 (level,dir)
        zero_cnt_kernel<<<1172, 256, 0, stream>>>(cnt);
        hist_kernel<<<dim3(1172, 6), 256, 0, stream>>>(idx, cnt);
        scan1_kernel<<<dim3(196, 6), 256, 0, stream>>>(cnt, rptmp, bsum);
        scan2_kernel<<<6, 256, 0, stream>>>(bsum);
        scan3_kernel<<<dim3(196, 6), 256, 0, stream>>>(cnt, rptmp, bsum, rowptr, cursor);
        scatter_kernel<<<dim3(1172, 6), 256, 0, stream>>>(idx, cursor, pos);

        wtrans_kernel<<<32, 256, 0, stream>>>(W_up, W_down, WtU, WtD);
        init2_kernel<<<9375, 256, 0, stream>>>(x0, x1, x2, agg, xh);

        for (int d = 0; d < 3; ++d) {
            const float* x  = (const float*)d_in[5 * d + 0];
            const int*   ui = (const int*)  d_in[5 * d + 1];
            const int*   di = (const int*)  d_in[5 * d + 2];
            const float* ua = (const float*)d_in[5 * d + 3];
            const float* da = (const float*)d_in[5 * d + 4];
            const f16* xhd = xh + (size_t)d * NN * 64;
            edge_mlp_kernel<<<dim3(4688, 2), 256, 0, stream>>>(
                xhd, ui, di, ua, da, WtU, WtD, b_up, b_down,
                pos + (size_t)(2 * d) * NE, pos + (size_t)(2 * d + 1) * NE, mU, mD);
            agg_kernel<<<3125, 256, 0, stream>>>(
                x, mU, mD,
                rowptr + (size_t)(2 * d) * (NN + 1), rowptr + (size_t)(2 * d + 1) * (NN + 1),
                agg + (size_t)d * NN * 64);
        }
        node_kernel<<<586, 256, 0, stream>>>(agg, (float*)d_out, W1, b1, W2, b2);
    } else if (ws_size >= fallback_need) {
        // round-5 proven atomic path
        wtrans_kernel<<<32, 256, 0, stream>>>(W_up, W_down, WtU, WtD);
        init2_kernel<<<9375, 256, 0, stream>>>(x0, x1, x2, agg, xh);
        for (int d = 0; d < 3; ++d) {
            const int*   ui = (const int*)  d_in[5 * d + 1];
            const int*   di = (const int*)  d_in[5 * d + 2];
            const float* ua = (const float*)d_in[5 * d + 3];
            const float* da = (const float*)d_in[5 * d + 4];
            const f16* xhd = xh + (size_t)d * NN * 64;
            __half* h = (__half*)(agg + (size_t)d * NN * 64);
            edge4_kernel<<<dim3(1024, 2), 256, 0, stream>>>(
                xhd, ui, di, ua, da, WtU, WtD, b_up, b_down, h);
        }
        node_kernel<<<586, 256, 0, stream>>>(agg, (float*)d_out, W1, b1, W2, b2);
    }
}